// Round 1
// baseline (486.622 us; speedup 1.0000x reference)
//
#include <hip/hip_runtime.h>
#include <hip/hip_bf16.h>
#include <stdint.h>

// ---------- types ----------
typedef __attribute__((ext_vector_type(8))) short short8;   // 8 bf16 in 4 VGPRs
typedef __attribute__((ext_vector_type(4))) float floatx4;  // MFMA accumulator

__device__ __forceinline__ ushort f2bf(float f) {
    union { float f; uint32_t u; } v; v.f = f;
    uint32_t u = v.u;
    uint32_t r = (u + 0x7FFFu + ((u >> 16) & 1u)) >> 16;   // RNE
    return (ushort)r;
}
__device__ __forceinline__ float bf2f(ushort b) {
    union { uint32_t u; float f; } v; v.u = ((uint32_t)b) << 16;
    return v.f;
}

// ---------- kernel 1: fp32 -> bf16 bulk convert (x) ----------
__global__ void cvt_bf16_kernel(const float* __restrict__ src, ushort* __restrict__ dst, int n4) {
    int i = blockIdx.x * blockDim.x + threadIdx.x;   // one float4 per thread
    if (i >= n4) return;
    const float4* s4 = (const float4*)src;
    float4 v = s4[i];
    ushort4 o;
    o.x = f2bf(v.x); o.y = f2bf(v.y); o.z = f2bf(v.z); o.w = f2bf(v.w);
    ((ushort4*)dst)[i] = o;
}

// ---------- kernel 2: transpose fp32 (R x N) -> bf16 (N x R) ----------
__global__ void transpose_bf16_kernel(const float* __restrict__ src, ushort* __restrict__ dst,
                                      int R, int N) {
    __shared__ float tile[32][33];
    int c0 = blockIdx.x * 32;
    int r0 = blockIdx.y * 32;
    int tx = threadIdx.x;        // 0..31
    int ty = threadIdx.y;        // 0..7
    for (int i = ty; i < 32; i += 8)
        tile[i][tx] = src[(size_t)(r0 + i) * N + c0 + tx];
    __syncthreads();
    for (int i = ty; i < 32; i += 8)
        dst[(size_t)(c0 + i) * R + r0 + tx] = f2bf(tile[tx][i]);
}

// ---------- kernel 3: last_ix + gather x[t] row as bf16 ----------
__global__ void lastix_gather_kernel(const int* __restrict__ mask, const float* __restrict__ x,
                                     ushort* __restrict__ xq, int* __restrict__ lastix) {
    int bw = blockIdx.x;               // 0..1023
    int s = 0;
    #pragma unroll
    for (int j = 0; j < 32; ++j) s += mask[bw * 32 + j];
    int t = s - 1;
    if (threadIdx.x == 0) lastix[bw] = t;
    const float* row = x + ((size_t)bw * 32 + t) * 1024;
    for (int i = threadIdx.x; i < 1024; i += 256)
        xq[(size_t)bw * 1024 + i] = f2bf(row[i]);
}

// ---------- kernel 4: m97-style GEMM, C[m][n] = sum_k A[m][k]*Bt[n][k] ----------
// A: (M x K) bf16 row-major, Bt: (N x K) bf16 row-major, K multiple of 32,
// M,N multiples of 128. OUT_BF16 selects bf16 vs f32 output.
template <bool OUT_BF16>
__global__ __launch_bounds__(256)
void gemm_bt_kernel(const ushort* __restrict__ A, const ushort* __restrict__ Bt,
                    void* __restrict__ C, int M, int N, int K) {
    __shared__ ushort As[128 * 32];
    __shared__ ushort Bs[128 * 32];

    const int bm = blockIdx.x;
    const int bn = blockIdx.y;
    const int tid  = threadIdx.x;
    const int wave = tid >> 6;
    const int lane = tid & 63;
    const int wm = wave & 1;          // 2x2 wave grid over the 128x128 tile
    const int wn = wave >> 1;
    const int quad = lane >> 4;
    const int l15  = lane & 15;

    floatx4 acc[4][4] = {};

    const int arow = bm * 128 + wave * 16 + (lane >> 2);
    const int brow = bn * 128 + wave * 16 + (lane >> 2);
    const int kcol = (lane & 3) * 8;

    for (int kt = 0; kt < K; kt += 32) {
        #pragma unroll
        for (int iss = 0; iss < 2; ++iss) {
            const ushort* gA = A  + (size_t)(arow + iss * 64) * K + kt + kcol;
            const ushort* gB = Bt + (size_t)(brow + iss * 64) * K + kt + kcol;
            ushort* lA = As + (iss * 64 + wave * 16) * 32;   // wave-uniform base
            ushort* lB = Bs + (iss * 64 + wave * 16) * 32;
            __builtin_amdgcn_global_load_lds((const __attribute__((address_space(1))) void*)gA,
                                             (__attribute__((address_space(3))) void*)lA, 16, 0, 0);
            __builtin_amdgcn_global_load_lds((const __attribute__((address_space(1))) void*)gB,
                                             (__attribute__((address_space(3))) void*)lB, 16, 0, 0);
        }
        __syncthreads();

        short8 af[4], bf[4];
        #pragma unroll
        for (int i = 0; i < 4; ++i)
            af[i] = *(const short8*)&As[(wm * 64 + i * 16 + l15) * 32 + quad * 8];
        #pragma unroll
        for (int j = 0; j < 4; ++j)
            bf[j] = *(const short8*)&Bs[(wn * 64 + j * 16 + l15) * 32 + quad * 8];
        #pragma unroll
        for (int i = 0; i < 4; ++i)
            #pragma unroll
            for (int j = 0; j < 4; ++j)
                acc[i][j] = __builtin_amdgcn_mfma_f32_16x16x32_bf16(af[i], bf[j], acc[i][j], 0, 0, 0);
        __syncthreads();
    }

    // epilogue: D mapping col = lane&15, row = quad*4 + reg
    #pragma unroll
    for (int i = 0; i < 4; ++i) {
        #pragma unroll
        for (int j = 0; j < 4; ++j) {
            int r0 = bm * 128 + wm * 64 + i * 16 + quad * 4;
            int c  = bn * 128 + wn * 64 + j * 16 + l15;
            #pragma unroll
            for (int r = 0; r < 4; ++r) {
                float v = acc[i][j][r];
                if (OUT_BF16) ((ushort*)C)[(size_t)(r0 + r) * N + c] = f2bf(v);
                else          ((float*) C)[(size_t)(r0 + r) * N + c] = v;
            }
        }
    }
}

// ---------- kernel 5: attention (one wave per (bw, head), flash-style) ----------
__global__ void attn_kernel(const float* __restrict__ q, const ushort* __restrict__ kv,
                            const int* __restrict__ lastix, const float* __restrict__ pos_emb,
                            ushort* __restrict__ y) {
    int wave = threadIdx.x >> 6;
    int lane = threadIdx.x & 63;
    int unit = blockIdx.x * 4 + wave;     // 0..16383
    int bw = unit >> 4;                   // 0..1023
    int h  = unit & 15;
    int t  = lastix[bw];

    float qd = q[(size_t)bw * 1024 + h * 64 + lane] * 0.125f;  // 1/sqrt(64)
    const ushort* kbase = kv + (size_t)bw * 32 * 2048 + h * 64 + lane;

    float m = -1e30f, l = 0.f, o = 0.f;
    for (int j = 0; j <= t; ++j) {
        float kd = bf2f(kbase[(size_t)j * 2048]);
        float s = qd * kd;
        #pragma unroll
        for (int off = 32; off; off >>= 1) s += __shfl_xor(s, off);
        float vd = bf2f(kbase[(size_t)j * 2048 + 1024]);
        float mn = fmaxf(m, s);
        float alpha = __expf(m - mn);
        float p = __expf(s - mn);
        l = l * alpha + p;
        o = o * alpha + p * vd;
        m = mn;
    }
    o /= l;
    int w = bw & 255;   // bw = b*256 + w
    float out = o + pos_emb[(size_t)w * 1024 + h * 64 + lane];
    y[(size_t)bw * 1024 + h * 64 + lane] = f2bf(out);
}

// ---------- launch ----------
extern "C" void kernel_launch(void* const* d_in, const int* in_sizes, int n_in,
                              void* d_out, int out_size, void* d_ws, size_t ws_size,
                              hipStream_t stream) {
    const float* x        = (const float*)d_in[0];   // (4,256,32,1024)
    const int*   mask     = (const int*)  d_in[1];   // (4,256,32)
    const float* pos_emb  = (const float*)d_in[2];   // (256,1024)
    const float* attn_w   = (const float*)d_in[3];   // (1024,3072)
    const float* proj_w   = (const float*)d_in[4];   // (1024,1024)
    float*       out      = (float*)d_out;           // (4,256,1024) -> treated as (1024,1024)

    const int BW = 1024;          // B*W
    const int C  = 1024;
    const size_t NX = (size_t)BW * 32 * C;           // 33,554,432

    // workspace layout (bytes)
    char* ws = (char*)d_ws;
    ushort* x_bf   = (ushort*)(ws);                                   // 67,108,864 B
    ushort* kv_bf  = (ushort*)(ws + 67108864);                        // 134,217,728 B
    ushort* wt_bf  = (ushort*)(ws + 67108864 + 134217728);            // 6,291,456 B (3072 x 1024)
    ushort* pwt_bf = (ushort*)(ws + 67108864 + 134217728 + 6291456);  // 2,097,152 B (1024 x 1024)
    ushort* xq_bf  = (ushort*)(ws + 67108864 + 134217728 + 6291456 + 2097152);            // 2 MiB
    float*  q_f32  = (float*) (ws + 67108864 + 134217728 + 6291456 + 2097152 + 2097152);  // 4 MiB
    ushort* y_bf   = (ushort*)(ws + 67108864 + 134217728 + 6291456 + 2097152 + 2097152 + 4194304); // 2 MiB
    int*    lastix = (int*)   (ws + 67108864 + 134217728 + 6291456 + 2097152 + 2097152 + 4194304 + 2097152);

    // 1. x -> bf16
    cvt_bf16_kernel<<<(int)(NX / 4 / 256), 256, 0, stream>>>(x, x_bf, (int)(NX / 4));

    // 2. transpose weights -> bf16 (N x K layouts)
    transpose_bf16_kernel<<<dim3(3072 / 32, 1024 / 32), dim3(32, 8), 0, stream>>>(attn_w, wt_bf, 1024, 3072);
    transpose_bf16_kernel<<<dim3(1024 / 32, 1024 / 32), dim3(32, 8), 0, stream>>>(proj_w, pwt_bf, 1024, 1024);

    // 3. last_ix + gather query rows
    lastix_gather_kernel<<<BW, 256, 0, stream>>>(mask, x, xq_bf, lastix);

    // 4. K,V = X @ [Wk|Wv]   (M=32768, N=2048, K=1024), bf16 out
    gemm_bt_kernel<true><<<dim3(32768 / 128, 2048 / 128), 256, 0, stream>>>(
        x_bf, wt_bf + (size_t)1024 * 1024, (void*)kv_bf, 32768, 2048, 1024);

    // 5. Q_t = Xq @ Wq        (M=1024, N=1024, K=1024), f32 out
    gemm_bt_kernel<false><<<dim3(1024 / 128, 1024 / 128), 256, 0, stream>>>(
        xq_bf, wt_bf, (void*)q_f32, 1024, 1024, 1024);

    // 6. attention + pos_emb -> y (bf16)
    attn_kernel<<<16384 / 4, 256, 0, stream>>>(q_f32, kv_bf, lastix, pos_emb, y_bf);

    // 7. out = y @ proj_w     (M=1024, N=1024, K=1024), f32 out
    gemm_bt_kernel<false><<<dim3(1024 / 128, 1024 / 128), 256, 0, stream>>>(
        y_bf, pwt_bf, (void*)out, 1024, 1024, 1024);
}

// Round 2
// 405.633 us; speedup vs baseline: 1.1997x; 1.1997x over previous
//
#include <hip/hip_runtime.h>
#include <hip/hip_bf16.h>
#include <stdint.h>

// ---------- types ----------
typedef __attribute__((ext_vector_type(8))) short short8;   // 8 bf16 in 4 VGPRs
typedef __attribute__((ext_vector_type(4))) float floatx4;  // MFMA accumulator

__device__ __forceinline__ ushort f2bf(float f) {
    union { float f; uint32_t u; } v; v.f = f;
    uint32_t u = v.u;
    uint32_t r = (u + 0x7FFFu + ((u >> 16) & 1u)) >> 16;   // RNE
    return (ushort)r;
}
__device__ __forceinline__ float bf2f(ushort b) {
    union { uint32_t u; float f; } v; v.u = ((uint32_t)b) << 16;
    return v.f;
}

// ---------- kernel 1: per-window length, exclusive prefix (row_start), total count ----------
__global__ void prep_kernel(const int* __restrict__ mask, int* __restrict__ lastix,
                            int* __restrict__ row_start, int* __restrict__ mc) {
    __shared__ int sc[1024];
    int bw = threadIdx.x;                       // 1024 threads, one per window
    const int4* m4 = (const int4*)(mask + (size_t)bw * 32);
    int s = 0;
    #pragma unroll
    for (int i = 0; i < 8; ++i) { int4 v = m4[i]; s += v.x + v.y + v.z + v.w; }
    lastix[bw] = s - 1;
    sc[bw] = s;                                 // rows contributed = t+1 = s
    __syncthreads();
    for (int off = 1; off < 1024; off <<= 1) {  // Hillis-Steele inclusive scan
        int v = sc[bw];
        int add = (bw >= off) ? sc[bw - off] : 0;
        __syncthreads();
        sc[bw] = v + add;
        __syncthreads();
    }
    row_start[bw] = sc[bw] - s;                 // exclusive prefix
    if (bw == 1023) mc[0] = sc[bw];             // total compacted rows
}

// ---------- kernel 2: gather needed x rows -> compacted bf16; also query row ----------
__global__ void gather_kernel(const float* __restrict__ x, const int* __restrict__ lastix,
                              const int* __restrict__ row_start,
                              ushort* __restrict__ xc, ushort* __restrict__ xq) {
    int bw = blockIdx.x;
    int t  = lastix[bw];
    int rs = row_start[bw];
    const float4* src = (const float4*)(x + (size_t)bw * 32 * 1024);
    int n4 = (t + 1) * 256;                     // float4s to move
    for (int i = threadIdx.x; i < n4; i += 256) {
        float4 v = src[i];
        ushort4 o; o.x = f2bf(v.x); o.y = f2bf(v.y); o.z = f2bf(v.z); o.w = f2bf(v.w);
        int j = i >> 8, c4 = i & 255;
        ((ushort4*)(xc + (size_t)(rs + j) * 1024))[c4] = o;
        if (j == t) ((ushort4*)(xq + (size_t)bw * 1024))[c4] = o;
    }
}

// ---------- kernel 3: transpose fp32 (R x N) -> bf16 (N x R) ----------
__global__ void transpose_bf16_kernel(const float* __restrict__ src, ushort* __restrict__ dst,
                                      int R, int N) {
    __shared__ float tile[32][33];
    int c0 = blockIdx.x * 32;
    int r0 = blockIdx.y * 32;
    int tx = threadIdx.x;        // 0..31
    int ty = threadIdx.y;        // 0..7
    for (int i = ty; i < 32; i += 8)
        tile[i][tx] = src[(size_t)(r0 + i) * N + c0 + tx];
    __syncthreads();
    for (int i = ty; i < 32; i += 8)
        dst[(size_t)(c0 + i) * R + r0 + tx] = f2bf(tile[tx][i]);
}

// ---------- kernel 4: m97-style GEMM, C[m][n] = sum_k A[m][k]*Bt[n][k] ----------
// A: (M x K) bf16 row-major, Bt: (N x K) bf16 row-major, K multiple of 32,
// M,N multiples of 128. OUT_BF16 selects bf16 vs f32 output.
// m_limit: optional device row count — m-blocks entirely past it exit early.
template <bool OUT_BF16>
__global__ __launch_bounds__(256)
void gemm_bt_kernel(const ushort* __restrict__ A, const ushort* __restrict__ Bt,
                    void* __restrict__ C, int M, int N, int K,
                    const int* __restrict__ m_limit) {
    const int bm = blockIdx.x;
    if (m_limit && bm * 128 >= *m_limit) return;

    __shared__ ushort As[128 * 32];
    __shared__ ushort Bs[128 * 32];

    const int bn = blockIdx.y;
    const int tid  = threadIdx.x;
    const int wave = tid >> 6;
    const int lane = tid & 63;
    const int wm = wave & 1;          // 2x2 wave grid over the 128x128 tile
    const int wn = wave >> 1;
    const int quad = lane >> 4;
    const int l15  = lane & 15;

    floatx4 acc[4][4] = {};

    const int arow = bm * 128 + wave * 16 + (lane >> 2);
    const int brow = bn * 128 + wave * 16 + (lane >> 2);
    const int kcol = (lane & 3) * 8;

    for (int kt = 0; kt < K; kt += 32) {
        #pragma unroll
        for (int iss = 0; iss < 2; ++iss) {
            const ushort* gA = A  + (size_t)(arow + iss * 64) * K + kt + kcol;
            const ushort* gB = Bt + (size_t)(brow + iss * 64) * K + kt + kcol;
            ushort* lA = As + (iss * 64 + wave * 16) * 32;   // wave-uniform base
            ushort* lB = Bs + (iss * 64 + wave * 16) * 32;
            __builtin_amdgcn_global_load_lds((const __attribute__((address_space(1))) void*)gA,
                                             (__attribute__((address_space(3))) void*)lA, 16, 0, 0);
            __builtin_amdgcn_global_load_lds((const __attribute__((address_space(1))) void*)gB,
                                             (__attribute__((address_space(3))) void*)lB, 16, 0, 0);
        }
        __syncthreads();

        short8 af[4], bf[4];
        #pragma unroll
        for (int i = 0; i < 4; ++i)
            af[i] = *(const short8*)&As[(wm * 64 + i * 16 + l15) * 32 + quad * 8];
        #pragma unroll
        for (int j = 0; j < 4; ++j)
            bf[j] = *(const short8*)&Bs[(wn * 64 + j * 16 + l15) * 32 + quad * 8];
        #pragma unroll
        for (int i = 0; i < 4; ++i)
            #pragma unroll
            for (int j = 0; j < 4; ++j)
                acc[i][j] = __builtin_amdgcn_mfma_f32_16x16x32_bf16(af[i], bf[j], acc[i][j], 0, 0, 0);
        __syncthreads();
    }

    // epilogue: D mapping col = lane&15, row = quad*4 + reg
    #pragma unroll
    for (int i = 0; i < 4; ++i) {
        #pragma unroll
        for (int j = 0; j < 4; ++j) {
            int r0 = bm * 128 + wm * 64 + i * 16 + quad * 4;
            int c  = bn * 128 + wn * 64 + j * 16 + l15;
            #pragma unroll
            for (int r = 0; r < 4; ++r) {
                float v = acc[i][j][r];
                if (OUT_BF16) ((ushort*)C)[(size_t)(r0 + r) * N + c] = f2bf(v);
                else          ((float*) C)[(size_t)(r0 + r) * N + c] = v;
            }
        }
    }
}

// ---------- kernel 5: attention (one wave per (bw, head), flash-style) ----------
__global__ void attn_kernel(const float* __restrict__ q, const ushort* __restrict__ kv,
                            const int* __restrict__ lastix, const int* __restrict__ row_start,
                            const float* __restrict__ pos_emb, ushort* __restrict__ y) {
    int wave = threadIdx.x >> 6;
    int lane = threadIdx.x & 63;
    int unit = blockIdx.x * 4 + wave;     // 0..16383
    int bw = unit >> 4;                   // 0..1023
    int h  = unit & 15;
    int t  = lastix[bw];
    int rs = row_start[bw];

    float qd = q[(size_t)bw * 1024 + h * 64 + lane] * 0.125f;  // 1/sqrt(64)
    const ushort* kbase = kv + (size_t)rs * 2048 + h * 64 + lane;

    float m = -1e30f, l = 0.f, o = 0.f;
    for (int j = 0; j <= t; ++j) {
        float kd = bf2f(kbase[(size_t)j * 2048]);
        float s = qd * kd;
        #pragma unroll
        for (int off = 32; off; off >>= 1) s += __shfl_xor(s, off);
        float vd = bf2f(kbase[(size_t)j * 2048 + 1024]);
        float mn = fmaxf(m, s);
        float alpha = __expf(m - mn);
        float p = __expf(s - mn);
        l = l * alpha + p;
        o = o * alpha + p * vd;
        m = mn;
    }
    o /= l;
    int w = bw & 255;   // bw = b*256 + w
    float out = o + pos_emb[(size_t)w * 1024 + h * 64 + lane];
    y[(size_t)bw * 1024 + h * 64 + lane] = f2bf(out);
}

// ---------- launch ----------
extern "C" void kernel_launch(void* const* d_in, const int* in_sizes, int n_in,
                              void* d_out, int out_size, void* d_ws, size_t ws_size,
                              hipStream_t stream) {
    const float* x        = (const float*)d_in[0];   // (4,256,32,1024)
    const int*   mask     = (const int*)  d_in[1];   // (4,256,32)
    const float* pos_emb  = (const float*)d_in[2];   // (256,1024)
    const float* attn_w   = (const float*)d_in[3];   // (1024,3072)
    const float* proj_w   = (const float*)d_in[4];   // (1024,1024)
    float*       out      = (float*)d_out;           // (4,256,1024) -> (1024,1024)

    const int BW = 1024;          // B*W

    // workspace layout (bytes)
    char* ws = (char*)d_ws;
    size_t off = 0;
    ushort* xc_bf  = (ushort*)(ws + off); off += (size_t)32768 * 1024 * 2;   // 64 MiB compacted x
    ushort* kv_bf  = (ushort*)(ws + off); off += (size_t)32768 * 2048 * 2;   // 128 MiB compacted K|V
    ushort* wt_bf  = (ushort*)(ws + off); off += (size_t)3072 * 1024 * 2;    // 6 MiB  Wqkv^T
    ushort* pwt_bf = (ushort*)(ws + off); off += (size_t)1024 * 1024 * 2;    // 2 MiB  Wproj^T
    ushort* xq_bf  = (ushort*)(ws + off); off += (size_t)1024 * 1024 * 2;    // 2 MiB  query rows
    float*  q_f32  = (float*) (ws + off); off += (size_t)1024 * 1024 * 4;    // 4 MiB
    ushort* y_bf   = (ushort*)(ws + off); off += (size_t)1024 * 1024 * 2;    // 2 MiB
    int*    lastix = (int*)   (ws + off); off += 4096;
    int*    rowst  = (int*)   (ws + off); off += 4096;
    int*    mc     = (int*)   (ws + off); off += 256;

    // 1. lengths, prefix sums, total row count
    prep_kernel<<<1, 1024, 0, stream>>>(mask, lastix, rowst, mc);

    // 2. gather needed rows (fused fp32->bf16), plus query rows
    gather_kernel<<<BW, 256, 0, stream>>>(x, lastix, rowst, xc_bf, xq_bf);

    // 3. transpose weights -> bf16 (N x K layouts)
    transpose_bf16_kernel<<<dim3(3072 / 32, 1024 / 32), dim3(32, 8), 0, stream>>>(attn_w, wt_bf, 1024, 3072);
    transpose_bf16_kernel<<<dim3(1024 / 32, 1024 / 32), dim3(32, 8), 0, stream>>>(proj_w, pwt_bf, 1024, 1024);

    // 4. K,V = Xc @ [Wk|Wv]   (M<=32768 data-dependent, N=2048, K=1024), bf16 out
    gemm_bt_kernel<true><<<dim3(32768 / 128, 2048 / 128), 256, 0, stream>>>(
        xc_bf, wt_bf + (size_t)1024 * 1024, (void*)kv_bf, 32768, 2048, 1024, mc);

    // 5. Q_t = Xq @ Wq        (M=1024, N=1024, K=1024), f32 out
    gemm_bt_kernel<false><<<dim3(1024 / 128, 1024 / 128), 256, 0, stream>>>(
        xq_bf, wt_bf, (void*)q_f32, 1024, 1024, 1024, nullptr);

    // 6. attention + pos_emb -> y (bf16)
    attn_kernel<<<16384 / 4, 256, 0, stream>>>(q_f32, kv_bf, lastix, rowst, pos_emb, y_bf);

    // 7. out = y @ proj_w     (M=1024, N=1024, K=1024), f32 out
    gemm_bt_kernel<false><<<dim3(1024 / 128, 1024 / 128), 256, 0, stream>>>(
        y_bf, pwt_bf, (void*)out, 1024, 1024, 1024, nullptr);
}

// Round 3
// 372.838 us; speedup vs baseline: 1.3052x; 1.0880x over previous
//
#include <hip/hip_runtime.h>
#include <hip/hip_bf16.h>
#include <stdint.h>

// ---------- types ----------
typedef __attribute__((ext_vector_type(8))) short short8;   // 8 bf16 in 4 VGPRs
typedef __attribute__((ext_vector_type(4))) float floatx4;  // MFMA accumulator

#define GPTR(p) (const __attribute__((address_space(1))) void*)(p)
#define LPTR(p) (__attribute__((address_space(3))) void*)(p)

__device__ __forceinline__ ushort f2bf(float f) {
    union { float f; uint32_t u; } v; v.f = f;
    uint32_t u = v.u;
    uint32_t r = (u + 0x7FFFu + ((u >> 16) & 1u)) >> 16;   // RNE
    return (ushort)r;
}
__device__ __forceinline__ float bf2f(ushort b) {
    union { uint32_t u; float f; } v; v.u = ((uint32_t)b) << 16;
    return v.f;
}

// ---------- kernel 1: lengths + exclusive prefix via wave scan (3 barriers) ----------
__global__ void prep_kernel(const int* __restrict__ mask, int* __restrict__ lastix,
                            int* __restrict__ row_start, int* __restrict__ mc) {
    __shared__ int wsum[16];
    int tid = threadIdx.x;                      // 0..1023, one per window
    int wave = tid >> 6, lane = tid & 63;
    const int4* m4 = (const int4*)(mask + (size_t)tid * 32);
    int s = 0;
    #pragma unroll
    for (int i = 0; i < 8; ++i) { int4 v = m4[i]; s += v.x + v.y + v.z + v.w; }
    lastix[tid] = s - 1;
    int scan = s;                               // wave-inclusive scan
    #pragma unroll
    for (int off = 1; off < 64; off <<= 1) {
        int v = __shfl_up(scan, off);
        if (lane >= off) scan += v;
    }
    if (lane == 63) wsum[wave] = scan;
    __syncthreads();
    int base = 0;
    for (int w = 0; w < wave; ++w) base += wsum[w];
    int incl = base + scan;
    row_start[tid] = incl - s;                  // exclusive prefix
    if (tid == 1023) mc[0] = incl;              // total compacted rows
}

// ---------- kernel 2: gather needed x rows -> compacted bf16; also query row ----------
__global__ void gather_kernel(const float* __restrict__ x, const int* __restrict__ lastix,
                              const int* __restrict__ row_start,
                              ushort* __restrict__ xc, ushort* __restrict__ xq) {
    int bw = blockIdx.x;
    int t  = lastix[bw];
    int rs = row_start[bw];
    const float4* src = (const float4*)(x + (size_t)bw * 32 * 1024);
    int n4 = (t + 1) * 256;                     // float4s to move
    for (int i = threadIdx.x; i < n4; i += 256) {
        float4 v = src[i];
        ushort4 o; o.x = f2bf(v.x); o.y = f2bf(v.y); o.z = f2bf(v.z); o.w = f2bf(v.w);
        int j = i >> 8, c4 = i & 255;
        ((ushort4*)(xc + (size_t)(rs + j) * 1024))[c4] = o;
        if (j == t) ((ushort4*)(xq + (size_t)bw * 1024))[c4] = o;
    }
}

// ---------- kernel 3: fused transpose of both weights, fp32 (R x N) -> bf16 (N x R) ----------
__global__ void transpose2_kernel(const float* __restrict__ w1, ushort* __restrict__ d1,
                                  const float* __restrict__ w2, ushort* __restrict__ d2) {
    __shared__ float tile[32][33];
    int bx = blockIdx.x;                 // 0..95 -> attn_w (N=3072); 96..127 -> proj_w (N=1024)
    const float* src; ushort* dst; int N, cb;
    if (bx < 96) { src = w1; dst = d1; N = 3072; cb = bx; }
    else         { src = w2; dst = d2; N = 1024; cb = bx - 96; }
    const int R = 1024;
    int c0 = cb * 32;
    int r0 = blockIdx.y * 32;
    int tx = threadIdx.x, ty = threadIdx.y;
    for (int i = ty; i < 32; i += 8)
        tile[i][tx] = src[(size_t)(r0 + i) * N + c0 + tx];
    __syncthreads();
    for (int i = ty; i < 32; i += 8)
        dst[(size_t)(c0 + i) * R + r0 + tx] = f2bf(tile[tx][i]);
}

// ---------- kernel 4: m97-style 128x128 GEMM, C[m][n] = sum_k A[m][k]*Bt[n][k] ----------
template <bool OUT_BF16>
__global__ __launch_bounds__(256)
void gemm_bt_kernel(const ushort* __restrict__ A, const ushort* __restrict__ Bt,
                    void* __restrict__ C, int M, int N, int K,
                    const int* __restrict__ m_limit) {
    const int bm = blockIdx.x;
    if (m_limit && bm * 128 >= *m_limit) return;

    __shared__ ushort As[128 * 32];
    __shared__ ushort Bs[128 * 32];

    const int bn = blockIdx.y;
    const int tid  = threadIdx.x;
    const int wave = tid >> 6;
    const int lane = tid & 63;
    const int wm = wave & 1;
    const int wn = wave >> 1;
    const int quad = lane >> 4;
    const int l15  = lane & 15;

    floatx4 acc[4][4] = {};

    const int arow = bm * 128 + wave * 16 + (lane >> 2);
    const int brow = bn * 128 + wave * 16 + (lane >> 2);
    const int kcol = (lane & 3) * 8;

    for (int kt = 0; kt < K; kt += 32) {
        #pragma unroll
        for (int iss = 0; iss < 2; ++iss) {
            const ushort* gA = A  + (size_t)(arow + iss * 64) * K + kt + kcol;
            const ushort* gB = Bt + (size_t)(brow + iss * 64) * K + kt + kcol;
            ushort* lA = As + (iss * 64 + wave * 16) * 32;
            ushort* lB = Bs + (iss * 64 + wave * 16) * 32;
            __builtin_amdgcn_global_load_lds(GPTR(gA), LPTR(lA), 16, 0, 0);
            __builtin_amdgcn_global_load_lds(GPTR(gB), LPTR(lB), 16, 0, 0);
        }
        __syncthreads();

        short8 af[4], bf[4];
        #pragma unroll
        for (int i = 0; i < 4; ++i)
            af[i] = *(const short8*)&As[(wm * 64 + i * 16 + l15) * 32 + quad * 8];
        #pragma unroll
        for (int j = 0; j < 4; ++j)
            bf[j] = *(const short8*)&Bs[(wn * 64 + j * 16 + l15) * 32 + quad * 8];
        #pragma unroll
        for (int i = 0; i < 4; ++i)
            #pragma unroll
            for (int j = 0; j < 4; ++j)
                acc[i][j] = __builtin_amdgcn_mfma_f32_16x16x32_bf16(af[i], bf[j], acc[i][j], 0, 0, 0);
        __syncthreads();
    }

    #pragma unroll
    for (int i = 0; i < 4; ++i) {
        #pragma unroll
        for (int j = 0; j < 4; ++j) {
            int r0 = bm * 128 + wm * 64 + i * 16 + quad * 4;
            int c  = bn * 128 + wn * 64 + j * 16 + l15;
            #pragma unroll
            for (int r = 0; r < 4; ++r) {
                float v = acc[i][j][r];
                if (OUT_BF16) ((ushort*)C)[(size_t)(r0 + r) * N + c] = f2bf(v);
                else          ((float*) C)[(size_t)(r0 + r) * N + c] = v;
            }
        }
    }
}

// ---------- kernel 4b: 64x64-tile GEMM (f32 out) for small M,N — 4x more blocks ----------
__global__ __launch_bounds__(256)
void gemm_bt64_kernel(const ushort* __restrict__ A, const ushort* __restrict__ Bt,
                      float* __restrict__ C, int M, int N, int K) {
    __shared__ ushort As[64 * 32];
    __shared__ ushort Bs[64 * 32];

    const int bm = blockIdx.x;
    const int bn = blockIdx.y;
    const int tid  = threadIdx.x;
    const int wave = tid >> 6;
    const int lane = tid & 63;
    const int wm = wave & 1;
    const int wn = wave >> 1;
    const int quad = lane >> 4;
    const int l15  = lane & 15;

    floatx4 acc[2][2] = {};

    const int srow = wave * 16 + (lane >> 2);       // staged row within 64-tile
    const int kcol = (lane & 3) * 8;

    for (int kt = 0; kt < K; kt += 32) {
        const ushort* gA = A  + (size_t)(bm * 64 + srow) * K + kt + kcol;
        const ushort* gB = Bt + (size_t)(bn * 64 + srow) * K + kt + kcol;
        ushort* lA = As + (wave * 16) * 32;         // wave-uniform base
        ushort* lB = Bs + (wave * 16) * 32;
        __builtin_amdgcn_global_load_lds(GPTR(gA), LPTR(lA), 16, 0, 0);
        __builtin_amdgcn_global_load_lds(GPTR(gB), LPTR(lB), 16, 0, 0);
        __syncthreads();

        short8 af[2], bf[2];
        #pragma unroll
        for (int i = 0; i < 2; ++i)
            af[i] = *(const short8*)&As[(wm * 32 + i * 16 + l15) * 32 + quad * 8];
        #pragma unroll
        for (int j = 0; j < 2; ++j)
            bf[j] = *(const short8*)&Bs[(wn * 32 + j * 16 + l15) * 32 + quad * 8];
        #pragma unroll
        for (int i = 0; i < 2; ++i)
            #pragma unroll
            for (int j = 0; j < 2; ++j)
                acc[i][j] = __builtin_amdgcn_mfma_f32_16x16x32_bf16(af[i], bf[j], acc[i][j], 0, 0, 0);
        __syncthreads();
    }

    #pragma unroll
    for (int i = 0; i < 2; ++i) {
        #pragma unroll
        for (int j = 0; j < 2; ++j) {
            int r0 = bm * 64 + wm * 32 + i * 16 + quad * 4;
            int c  = bn * 64 + wn * 32 + j * 16 + l15;
            #pragma unroll
            for (int r = 0; r < 4; ++r)
                C[(size_t)(r0 + r) * N + c] = acc[i][j][r];
        }
    }
}

// ---------- kernel 5: attention — 4 heads/wave, 8B KV loads, next-j prefetch ----------
__global__ void attn_kernel(const float* __restrict__ q, const ushort* __restrict__ kv,
                            const int* __restrict__ lastix, const int* __restrict__ row_start,
                            const float* __restrict__ pos_emb, ushort* __restrict__ y) {
    int wave = threadIdx.x >> 6;          // head-group 0..3 (heads hg*4 .. hg*4+3)
    int lane = threadIdx.x & 63;
    int bw = blockIdx.x;                  // 0..1023
    int hg = wave;
    int t  = lastix[bw];
    int rs = row_start[bw];
    int col = hg * 256 + lane * 4;        // lane covers 4 dims of head hg*4+(lane>>4)

    float4 q4 = *(const float4*)(q + (size_t)bw * 1024 + col);
    q4.x *= 0.125f; q4.y *= 0.125f; q4.z *= 0.125f; q4.w *= 0.125f;   // 1/sqrt(64)

    const ushort* base = kv + (size_t)rs * 2048 + col;
    ushort4 kc = *(const ushort4*)(base);
    ushort4 vc = *(const ushort4*)(base + 1024);

    float m = -1e30f, l = 0.f;
    float4 o = {0.f, 0.f, 0.f, 0.f};
    for (int j = 0; j <= t; ++j) {
        ushort4 kn, vn;
        if (j < t) {                       // wave-uniform branch; prefetch next row
            kn = *(const ushort4*)(base + (size_t)(j + 1) * 2048);
            vn = *(const ushort4*)(base + (size_t)(j + 1) * 2048 + 1024);
        }
        float s = q4.x * bf2f(kc.x) + q4.y * bf2f(kc.y) + q4.z * bf2f(kc.z) + q4.w * bf2f(kc.w);
        s += __shfl_xor(s, 1); s += __shfl_xor(s, 2);
        s += __shfl_xor(s, 4); s += __shfl_xor(s, 8);   // reduce 16 lanes -> head score
        float mn = fmaxf(m, s);
        float alpha = __expf(m - mn);
        float p = __expf(s - mn);
        l = l * alpha + p;
        o.x = o.x * alpha + p * bf2f(vc.x);
        o.y = o.y * alpha + p * bf2f(vc.y);
        o.z = o.z * alpha + p * bf2f(vc.z);
        o.w = o.w * alpha + p * bf2f(vc.w);
        m = mn;
        kc = kn; vc = vn;
    }
    float inv = 1.f / l;
    const float4 pe = *(const float4*)(pos_emb + (size_t)(bw & 255) * 1024 + col);
    ushort4 r;
    r.x = f2bf(o.x * inv + pe.x);
    r.y = f2bf(o.y * inv + pe.y);
    r.z = f2bf(o.z * inv + pe.z);
    r.w = f2bf(o.w * inv + pe.w);
    *(ushort4*)(y + (size_t)bw * 1024 + col) = r;
}

// ---------- launch ----------
extern "C" void kernel_launch(void* const* d_in, const int* in_sizes, int n_in,
                              void* d_out, int out_size, void* d_ws, size_t ws_size,
                              hipStream_t stream) {
    const float* x        = (const float*)d_in[0];   // (4,256,32,1024)
    const int*   mask     = (const int*)  d_in[1];   // (4,256,32)
    const float* pos_emb  = (const float*)d_in[2];   // (256,1024)
    const float* attn_w   = (const float*)d_in[3];   // (1024,3072)
    const float* proj_w   = (const float*)d_in[4];   // (1024,1024)
    float*       out      = (float*)d_out;           // (1024,1024)

    const int BW = 1024;

    char* ws = (char*)d_ws;
    size_t off = 0;
    ushort* xc_bf  = (ushort*)(ws + off); off += (size_t)32768 * 1024 * 2;   // compacted x
    ushort* kv_bf  = (ushort*)(ws + off); off += (size_t)32768 * 2048 * 2;   // compacted K|V
    ushort* wt_bf  = (ushort*)(ws + off); off += (size_t)3072 * 1024 * 2;    // Wqkv^T
    ushort* pwt_bf = (ushort*)(ws + off); off += (size_t)1024 * 1024 * 2;    // Wproj^T
    ushort* xq_bf  = (ushort*)(ws + off); off += (size_t)1024 * 1024 * 2;    // query rows
    float*  q_f32  = (float*) (ws + off); off += (size_t)1024 * 1024 * 4;
    ushort* y_bf   = (ushort*)(ws + off); off += (size_t)1024 * 1024 * 2;
    int*    lastix = (int*)   (ws + off); off += 4096;
    int*    rowst  = (int*)   (ws + off); off += 4096;
    int*    mc     = (int*)   (ws + off); off += 256;

    // 1. lengths + prefix sums
    prep_kernel<<<1, 1024, 0, stream>>>(mask, lastix, rowst, mc);

    // 2. both weight transposes in one dispatch
    transpose2_kernel<<<dim3(128, 32), dim3(32, 8), 0, stream>>>(attn_w, wt_bf, proj_w, pwt_bf);

    // 3. gather needed rows (fused fp32->bf16) + query rows
    gather_kernel<<<BW, 256, 0, stream>>>(x, lastix, rowst, xc_bf, xq_bf);

    // 4. Q_t = Xq @ Wq        (1024 x 1024 x 1024), 64-tile, f32 out
    gemm_bt64_kernel<<<dim3(16, 16), 256, 0, stream>>>(xq_bf, wt_bf, q_f32, 1024, 1024, 1024);

    // 5. K,V = Xc @ [Wk|Wv]   (M<=32768 data-dependent, N=2048, K=1024), bf16 out
    gemm_bt_kernel<true><<<dim3(32768 / 128, 2048 / 128), 256, 0, stream>>>(
        xc_bf, wt_bf + (size_t)1024 * 1024, (void*)kv_bf, 32768, 2048, 1024, mc);

    // 6. attention + pos_emb -> y (bf16)
    attn_kernel<<<BW, 256, 0, stream>>>(q_f32, kv_bf, lastix, rowst, pos_emb, y_bf);

    // 7. out = y @ proj_w     (1024 x 1024 x 1024), 64-tile, f32 out
    gemm_bt64_kernel<<<dim3(16, 16), 256, 0, stream>>>(y_bf, pwt_bf, out, 1024, 1024, 1024);
}

// Round 4
// 315.126 us; speedup vs baseline: 1.5442x; 1.1831x over previous
//
#include <hip/hip_runtime.h>
#include <hip/hip_bf16.h>
#include <stdint.h>

// ---------- types ----------
typedef __attribute__((ext_vector_type(8))) short short8;   // 8 bf16 in 4 VGPRs
typedef __attribute__((ext_vector_type(4))) float floatx4;  // MFMA accumulator

#define GPTR(p) (const __attribute__((address_space(1))) void*)(p)
#define LPTR(p) (__attribute__((address_space(3))) void*)(p)

__device__ __forceinline__ ushort f2bf(float f) {
    union { float f; uint32_t u; } v; v.f = f;
    uint32_t u = v.u;
    uint32_t r = (u + 0x7FFFu + ((u >> 16) & 1u)) >> 16;   // RNE
    return (ushort)r;
}
__device__ __forceinline__ float bf2f(ushort b) {
    union { uint32_t u; float f; } v; v.u = ((uint32_t)b) << 16;
    return v.f;
}

// ---------- kernel 1: lengths + exclusive prefix via wave scan ----------
__global__ void prep_kernel(const int* __restrict__ mask, int* __restrict__ lastix,
                            int* __restrict__ row_start, int* __restrict__ mc) {
    __shared__ int wsum[16];
    int tid = threadIdx.x;                      // 0..1023, one per window
    int wave = tid >> 6, lane = tid & 63;
    const int4* m4 = (const int4*)(mask + (size_t)tid * 32);
    int s = 0;
    #pragma unroll
    for (int i = 0; i < 8; ++i) { int4 v = m4[i]; s += v.x + v.y + v.z + v.w; }
    lastix[tid] = s - 1;
    int scan = s;
    #pragma unroll
    for (int off = 1; off < 64; off <<= 1) {
        int v = __shfl_up(scan, off);
        if (lane >= off) scan += v;
    }
    if (lane == 63) wsum[wave] = scan;
    __syncthreads();
    int base = 0;
    for (int w = 0; w < wave; ++w) base += wsum[w];
    int incl = base + scan;
    row_start[tid] = incl - s;
    if (tid == 1023) mc[0] = incl;
}

// ---------- kernel 2: gather needed x rows -> compacted bf16; also query row ----------
__global__ void gather_kernel(const float* __restrict__ x, const int* __restrict__ lastix,
                              const int* __restrict__ row_start,
                              ushort* __restrict__ xc, ushort* __restrict__ xq) {
    int bw = blockIdx.x;
    int t  = lastix[bw];
    int rs = row_start[bw];
    const float4* src = (const float4*)(x + (size_t)bw * 32 * 1024);
    int n4 = (t + 1) * 256;
    for (int i = threadIdx.x; i < n4; i += 256) {
        float4 v = src[i];
        ushort4 o; o.x = f2bf(v.x); o.y = f2bf(v.y); o.z = f2bf(v.z); o.w = f2bf(v.w);
        int j = i >> 8, c4 = i & 255;
        ((ushort4*)(xc + (size_t)(rs + j) * 1024))[c4] = o;
        if (j == t) ((ushort4*)(xq + (size_t)bw * 1024))[c4] = o;
    }
}

// ---------- kernel 3: weight prep (fused): WqT, WvT, WpT transposes + Wk cast ----------
__global__ void wcvt_kernel(const float* __restrict__ attn_w, const float* __restrict__ proj_w,
                            ushort* __restrict__ wqT, ushort* __restrict__ wk,
                            ushort* __restrict__ wvT, ushort* __restrict__ wpT) {
    __shared__ float tile[32][33];
    int bx = blockIdx.x;                 // 0..127
    int r0 = blockIdx.y * 32;
    int tx = threadIdx.x, ty = threadIdx.y;
    if (bx >= 96) {                      // cast path: wk[r][c] = attn_w[r][1024+c]
        int c0 = (bx - 96) * 32;
        for (int i = ty; i < 32; i += 8)
            wk[(size_t)(r0 + i) * 1024 + c0 + tx] =
                f2bf(attn_w[(size_t)(r0 + i) * 3072 + 1024 + c0 + tx]);
        return;
    }
    const float* src; ushort* dst; int N, csrc0, c0;
    if (bx < 32)      { src = attn_w; dst = wqT; N = 3072; c0 = bx * 32;        csrc0 = c0; }
    else if (bx < 64) { src = attn_w; dst = wvT; N = 3072; c0 = (bx - 32) * 32; csrc0 = 2048 + c0; }
    else              { src = proj_w; dst = wpT; N = 1024; c0 = (bx - 64) * 32; csrc0 = c0; }
    for (int i = ty; i < 32; i += 8)
        tile[i][tx] = src[(size_t)(r0 + i) * N + csrc0 + tx];
    __syncthreads();
    for (int i = ty; i < 32; i += 8)
        dst[(size_t)(c0 + i) * 1024 + r0 + tx] = f2bf(tile[tx][i]);
}

// ---------- kernel 4: 128-tile GEMM (batched/strided), C[m][n] = sum_k A[m][k]*Bt[n][k] ----------
template <bool OUT_BF16>
__global__ __launch_bounds__(256)
void gemm128_kernel(const ushort* __restrict__ A, int lda, long sA,
                    const ushort* __restrict__ Bt, int ldb, long sB,
                    void* __restrict__ C, int ldc, long sC, int K) {
    __shared__ ushort As[128 * 32];
    __shared__ ushort Bs[128 * 32];

    const int bm = blockIdx.x, bn = blockIdx.y, z = blockIdx.z;
    A  += (size_t)z * sA;
    Bt += (size_t)z * sB;

    const int tid  = threadIdx.x;
    const int wave = tid >> 6;
    const int lane = tid & 63;
    const int wm = wave & 1, wn = wave >> 1;
    const int quad = lane >> 4, l15 = lane & 15;

    floatx4 acc[4][4] = {};

    const int arow = bm * 128 + wave * 16 + (lane >> 2);
    const int brow = bn * 128 + wave * 16 + (lane >> 2);
    const int kcol = (lane & 3) * 8;

    for (int kt = 0; kt < K; kt += 32) {
        #pragma unroll
        for (int iss = 0; iss < 2; ++iss) {
            const ushort* gA = A  + (size_t)(arow + iss * 64) * lda + kt + kcol;
            const ushort* gB = Bt + (size_t)(brow + iss * 64) * ldb + kt + kcol;
            ushort* lA = As + (iss * 64 + wave * 16) * 32;
            ushort* lB = Bs + (iss * 64 + wave * 16) * 32;
            __builtin_amdgcn_global_load_lds(GPTR(gA), LPTR(lA), 16, 0, 0);
            __builtin_amdgcn_global_load_lds(GPTR(gB), LPTR(lB), 16, 0, 0);
        }
        __syncthreads();

        short8 af[4], bf[4];
        #pragma unroll
        for (int i = 0; i < 4; ++i)
            af[i] = *(const short8*)&As[(wm * 64 + i * 16 + l15) * 32 + quad * 8];
        #pragma unroll
        for (int j = 0; j < 4; ++j)
            bf[j] = *(const short8*)&Bs[(wn * 64 + j * 16 + l15) * 32 + quad * 8];
        #pragma unroll
        for (int i = 0; i < 4; ++i)
            #pragma unroll
            for (int j = 0; j < 4; ++j)
                acc[i][j] = __builtin_amdgcn_mfma_f32_16x16x32_bf16(af[i], bf[j], acc[i][j], 0, 0, 0);
        __syncthreads();
    }

    #pragma unroll
    for (int i = 0; i < 4; ++i) {
        #pragma unroll
        for (int j = 0; j < 4; ++j) {
            int r0 = bm * 128 + wm * 64 + i * 16 + quad * 4;
            int c  = bn * 128 + wn * 64 + j * 16 + l15;
            #pragma unroll
            for (int r = 0; r < 4; ++r) {
                float v = acc[i][j][r];
                size_t idx = (size_t)z * sC + (size_t)(r0 + r) * ldc + c;
                if (OUT_BF16) ((ushort*)C)[idx] = f2bf(v);
                else          ((float*) C)[idx] = v;
            }
        }
    }
}

// ---------- kernel 4b: 64-tile GEMM (batched/strided), optional pos-add epilogue ----------
template <bool OUT_BF16, bool ADD_POS>
__global__ __launch_bounds__(256)
void gemm64_kernel(const ushort* __restrict__ A, int lda, long sA,
                   const ushort* __restrict__ Bt, int ldb, long sB,
                   void* __restrict__ C, int ldc, int cColPerZ, int K,
                   const float* __restrict__ pos) {
    __shared__ ushort As[64 * 32];
    __shared__ ushort Bs[64 * 32];

    const int bm = blockIdx.x, bn = blockIdx.y, z = blockIdx.z;
    A  += (size_t)z * sA;
    Bt += (size_t)z * sB;

    const int tid  = threadIdx.x;
    const int wave = tid >> 6;
    const int lane = tid & 63;
    const int wm = wave & 1, wn = wave >> 1;
    const int quad = lane >> 4, l15 = lane & 15;

    floatx4 acc[2][2] = {};

    const int srow = wave * 16 + (lane >> 2);
    const int kcol = (lane & 3) * 8;

    for (int kt = 0; kt < K; kt += 32) {
        const ushort* gA = A  + (size_t)(bm * 64 + srow) * lda + kt + kcol;
        const ushort* gB = Bt + (size_t)(bn * 64 + srow) * ldb + kt + kcol;
        ushort* lA = As + (wave * 16) * 32;
        ushort* lB = Bs + (wave * 16) * 32;
        __builtin_amdgcn_global_load_lds(GPTR(gA), LPTR(lA), 16, 0, 0);
        __builtin_amdgcn_global_load_lds(GPTR(gB), LPTR(lB), 16, 0, 0);
        __syncthreads();

        short8 af[2], bf[2];
        #pragma unroll
        for (int i = 0; i < 2; ++i)
            af[i] = *(const short8*)&As[(wm * 32 + i * 16 + l15) * 32 + quad * 8];
        #pragma unroll
        for (int j = 0; j < 2; ++j)
            bf[j] = *(const short8*)&Bs[(wn * 32 + j * 16 + l15) * 32 + quad * 8];
        #pragma unroll
        for (int i = 0; i < 2; ++i)
            #pragma unroll
            for (int j = 0; j < 2; ++j)
                acc[i][j] = __builtin_amdgcn_mfma_f32_16x16x32_bf16(af[i], bf[j], acc[i][j], 0, 0, 0);
        __syncthreads();
    }

    #pragma unroll
    for (int i = 0; i < 2; ++i) {
        #pragma unroll
        for (int j = 0; j < 2; ++j) {
            int r0 = bm * 64 + wm * 32 + i * 16 + quad * 4;
            int cc = z * cColPerZ + bn * 64 + wn * 32 + j * 16 + l15;
            #pragma unroll
            for (int r = 0; r < 4; ++r) {
                float v = acc[i][j][r];
                if (ADD_POS) v += pos[(size_t)((r0 + r) & 255) * 1024 + cc];
                size_t idx = (size_t)(r0 + r) * ldc + cc;
                if (OUT_BF16) ((ushort*)C)[idx] = f2bf(v);
                else          ((float*) C)[idx] = v;
            }
        }
    }
}

// ---------- kernel 5: fused scores -> softmax -> Z, one block per window ----------
__global__ __launch_bounds__(256)
void attn2_kernel(const ushort* __restrict__ xc, const ushort* __restrict__ U,
                  const int* __restrict__ lastix, const int* __restrict__ row_start,
                  ushort* __restrict__ Z) {
    __shared__ ushort Xs[32 * 1032];   // X rows, padded stride (+8 bf16)
    __shared__ ushort Us[16 * 1032];   // u^h rows, padded
    __shared__ float  Ss[16 * 33];     // raw scores [h][j]
    __shared__ float  Ps[32 * 16];     // normalized probs [j][h] (broadcast-read)

    const int bw = blockIdx.x;
    const int tid = threadIdx.x;
    const int t  = lastix[bw];
    const int rs = row_start[bw];
    const int wave = tid >> 6, lane = tid & 63;
    const int quad = lane >> 4, l15 = lane & 15;

    // load X rows 0..t (source is contiguous) and U rows (16 x 1024)
    const ushort* xsrc = xc + (size_t)rs * 1024;
    int nv = (t + 1) * 128;                         // 8-elem chunks
    for (int i = tid; i < nv; i += 256) {
        int j = i >> 7, c = i & 127;
        *(short8*)&Xs[j * 1032 + c * 8] = *(const short8*)&xsrc[i * 8];
    }
    for (int i = tid; i < 16 * 128; i += 256) {
        int h = i >> 7, c = i & 127;
        *(short8*)&Us[h * 1032 + c * 8] =
            *(const short8*)&U[(size_t)h * 1048576 + (size_t)bw * 1024 + c * 8];
    }
    __syncthreads();

    // S = X(32x1024) @ U^T(16x1024): waves 0,1 each do one 16-row m-tile
    if (wave < 2) {
        floatx4 acc = {0.f, 0.f, 0.f, 0.f};
        int arow = wave * 16 + l15;
        for (int kt = 0; kt < 1024; kt += 32) {
            short8 a = *(const short8*)&Xs[arow * 1032 + kt + quad * 8];
            short8 b = *(const short8*)&Us[l15  * 1032 + kt + quad * 8];
            acc = __builtin_amdgcn_mfma_f32_16x16x32_bf16(a, b, acc, 0, 0, 0);
        }
        #pragma unroll
        for (int r = 0; r < 4; ++r)
            Ss[l15 * 33 + wave * 16 + quad * 4 + r] = acc[r] * 0.125f;
    }
    __syncthreads();

    // softmax per head (wave 0): h = l15, quad owns j = quad*8..quad*8+7
    if (wave == 0) {
        float s[8]; float mx = -1e30f;
        #pragma unroll
        for (int r = 0; r < 8; ++r) {
            int j = quad * 8 + r;
            float v = Ss[l15 * 33 + j];
            v = (j <= t) ? v : -1e30f;
            s[r] = v; mx = fmaxf(mx, v);
        }
        mx = fmaxf(mx, __shfl_xor(mx, 16));
        mx = fmaxf(mx, __shfl_xor(mx, 32));
        float l = 0.f;
        #pragma unroll
        for (int r = 0; r < 8; ++r) { s[r] = __expf(s[r] - mx); l += s[r]; }
        l += __shfl_xor(l, 16);
        l += __shfl_xor(l, 32);
        float inv = 1.f / l;
        #pragma unroll
        for (int r = 0; r < 8; ++r)
            Ps[(quad * 8 + r) * 16 + l15] = s[r] * inv;
    }
    __syncthreads();

    // Z[h][e] = sum_j P[j][h] * X[j][e]; thread owns 4 consecutive e
    float z[16][4];
    #pragma unroll
    for (int h = 0; h < 16; ++h)
        #pragma unroll
        for (int c = 0; c < 4; ++c) z[h][c] = 0.f;
    const int e0 = tid * 4;
    for (int j = 0; j <= t; ++j) {
        float4 p0 = *(const float4*)&Ps[j * 16 + 0];
        float4 p1 = *(const float4*)&Ps[j * 16 + 4];
        float4 p2 = *(const float4*)&Ps[j * 16 + 8];
        float4 p3 = *(const float4*)&Ps[j * 16 + 12];
        float pr[16] = {p0.x, p0.y, p0.z, p0.w, p1.x, p1.y, p1.z, p1.w,
                        p2.x, p2.y, p2.z, p2.w, p3.x, p3.y, p3.z, p3.w};
        ushort4 xv = *(const ushort4*)&Xs[j * 1032 + e0];
        float xf[4] = {bf2f(xv.x), bf2f(xv.y), bf2f(xv.z), bf2f(xv.w)};
        #pragma unroll
        for (int h = 0; h < 16; ++h)
            #pragma unroll
            for (int c = 0; c < 4; ++c)
                z[h][c] += pr[h] * xf[c];
    }
    #pragma unroll
    for (int h = 0; h < 16; ++h) {
        ushort4 o;
        o.x = f2bf(z[h][0]); o.y = f2bf(z[h][1]);
        o.z = f2bf(z[h][2]); o.w = f2bf(z[h][3]);
        *(ushort4*)&Z[(size_t)h * 1048576 + (size_t)bw * 1024 + e0] = o;
    }
}

// ---------- launch ----------
extern "C" void kernel_launch(void* const* d_in, const int* in_sizes, int n_in,
                              void* d_out, int out_size, void* d_ws, size_t ws_size,
                              hipStream_t stream) {
    const float* x        = (const float*)d_in[0];   // (4,256,32,1024)
    const int*   mask     = (const int*)  d_in[1];   // (4,256,32)
    const float* pos_emb  = (const float*)d_in[2];   // (256,1024)
    const float* attn_w   = (const float*)d_in[3];   // (1024,3072)
    const float* proj_w   = (const float*)d_in[4];   // (1024,1024)
    float*       out      = (float*)d_out;           // (1024,1024)

    const long MB2 = 1048576;                        // elements per 1024x1024 bf16 plane

    char* ws = (char*)d_ws;
    size_t off = 0;
    ushort* xc_bf = (ushort*)(ws + off); off += (size_t)32768 * 1024 * 2;   // 64 MiB compacted x
    ushort* U_bf  = (ushort*)(ws + off); off += (size_t)16 * MB2 * 2;       // 32 MiB U[h][bw][e]
    ushort* Z_bf  = (ushort*)(ws + off); off += (size_t)16 * MB2 * 2;       // 32 MiB Z[h][bw][e]
    ushort* wqT   = (ushort*)(ws + off); off += MB2 * 2;
    ushort* wk    = (ushort*)(ws + off); off += MB2 * 2;
    ushort* wvT   = (ushort*)(ws + off); off += MB2 * 2;
    ushort* wpT   = (ushort*)(ws + off); off += MB2 * 2;
    ushort* xq_bf = (ushort*)(ws + off); off += MB2 * 2;
    ushort* q_bf  = (ushort*)(ws + off); off += MB2 * 2;
    ushort* y_bf  = (ushort*)(ws + off); off += MB2 * 2;
    int*    lastix= (int*)   (ws + off); off += 4096;
    int*    rowst = (int*)   (ws + off); off += 4096;
    int*    mc    = (int*)   (ws + off); off += 256;

    // 1. lengths + prefix sums
    prep_kernel<<<1, 1024, 0, stream>>>(mask, lastix, rowst, mc);

    // 2. weight prep: WqT, WvT, WpT transposes + Wk cast (one dispatch)
    wcvt_kernel<<<dim3(128, 32), dim3(32, 8), 0, stream>>>(attn_w, proj_w, wqT, wk, wvT, wpT);

    // 3. gather needed rows (fused fp32->bf16) + query rows
    gather_kernel<<<1024, 256, 0, stream>>>(x, lastix, rowst, xc_bf, xq_bf);

    // 4. Q = Xq @ Wq  (1024x1024x1024), bf16 out
    gemm64_kernel<true, false><<<dim3(16, 16, 1), 256, 0, stream>>>(
        xq_bf, 1024, 0, wqT, 1024, 0, (void*)q_bf, 1024, 0, 1024, nullptr);

    // 5. U^h = Q^h @ (Wk^h)^T  — batched 16 x (1024x1024x64), bf16 out
    gemm128_kernel<true><<<dim3(8, 8, 16), 256, 0, stream>>>(
        q_bf, 1024, 64, wk, 1024, 64, (void*)U_bf, 1024, MB2, 64);

    // 6. fused scores -> softmax -> Z per window
    attn2_kernel<<<1024, 256, 0, stream>>>(xc_bf, U_bf, lastix, rowst, Z_bf);

    // 7. y = Z^h @ Wv^h + pos  — batched 16 x (1024x64x1024), bf16 out
    gemm64_kernel<true, true><<<dim3(16, 1, 16), 256, 0, stream>>>(
        Z_bf, 1024, MB2, wvT, 1024, 65536, (void*)y_bf, 1024, 64, 1024, pos_emb);

    // 8. out = y @ Wproj  (1024x1024x1024), f32 out
    gemm64_kernel<false, false><<<dim3(16, 16, 1), 256, 0, stream>>>(
        y_bf, 1024, 0, wpT, 1024, 0, (void*)out, 1024, 0, 1024, nullptr);
}